// Round 1
// baseline (2372.329 us; speedup 1.0000x reference)
//
#include <hip/hip_runtime.h>
#include <hip/hip_bf16.h>
#include <math.h>

typedef __hip_bfloat16 bf16;

#define EPSV 1e-5f

__device__ __forceinline__ float gelu_exact(float x) {
    return 0.5f * x * (1.0f + erff(x * 0.70710678118654752f));
}

// reduce (a,b) over the block; valid on thread 0. sm must hold >= 2*numwaves floats.
__device__ __forceinline__ void block_reduce2(float& a, float& b, float* sm) {
    #pragma unroll
    for (int off = 32; off > 0; off >>= 1) {
        a += __shfl_down(a, off);
        b += __shfl_down(b, off);
    }
    int lane = threadIdx.x & 63, wid = threadIdx.x >> 6;
    int nw = blockDim.x >> 6;
    if (lane == 0) { sm[wid*2] = a; sm[wid*2+1] = b; }
    __syncthreads();
    if (threadIdx.x == 0) {
        for (int i = 1; i < nw; ++i) { a += sm[i*2]; b += sm[i*2+1]; }
    }
}

__device__ __forceinline__ float2 bf2f(unsigned u) {
    float lo = __uint_as_float(u << 16);
    float hi = __uint_as_float(u & 0xffff0000u);
    return make_float2(lo, hi);
}

// ---------------- K0: GN0 stats over x (2M floats) ----------------
__global__ __launch_bounds__(256) void k0_stats_x(const float* __restrict__ x,
                                                  float* __restrict__ stats) {
    __shared__ float sm[16];
    const float4* x4 = (const float4*)x;
    int idx = blockIdx.x * 256 + threadIdx.x;
    float s = 0.f, q = 0.f;
    for (int i = idx; i < (1 << 19); i += gridDim.x * 256) {
        float4 v = x4[i];
        s += v.x + v.y + v.z + v.w;
        q += v.x*v.x + v.y*v.y + v.z*v.z + v.w*v.w;
    }
    block_reduce2(s, q, sm);
    if (threadIdx.x == 0) { atomicAdd(&stats[0], s); atomicAdd(&stats[1], q); }
}

// ---------------- KW: transpose w2 [o][ci][tap] -> wt [tap][ci][o] (bf16) ----------------
__global__ __launch_bounds__(256) void kw_transpose(const float* __restrict__ w2,
                                                    bf16* __restrict__ wt) {
    int idx = blockIdx.x * 256 + threadIdx.x;
    if (idx >= 81 * 128 * 128) return;
    int tap = idx >> 14;
    int r = idx & 16383;
    int ci = r >> 7;
    int o = r & 127;
    wt[idx] = __float2bfloat16(w2[(o * 128 + ci) * 81 + tap]);
}

// ---------------- K1: GN0-apply folded into conv1 (32->128), + GN1 stats ----------------
__global__ __launch_bounds__(256) void k1_conv1(
    const float* __restrict__ x, const float* __restrict__ w1,
    const float* __restrict__ g0w, const float* __restrict__ g0b,
    float* __restrict__ h1, float* __restrict__ stats)
{
    __shared__ float We[128 * 32];
    __shared__ float Be[128];
    __shared__ float sm[16];
    float mu = stats[0] * (1.f / 2097152.f);
    float var = stats[1] * (1.f / 2097152.f) - mu * mu;
    float rs = rsqrtf(var + EPSV);
    int t = threadIdx.x;
    for (int i = t; i < 128 * 32; i += 256) {
        int ci = i & 31;
        We[i] = w1[i] * g0w[ci] * rs;
    }
    if (t < 128) {
        float acc = 0.f;
        for (int ci = 0; ci < 32; ++ci)
            acc += w1[t * 32 + ci] * (g0b[ci] - mu * rs * g0w[ci]);
        Be[t] = acc;
    }
    __syncthreads();
    int s = blockIdx.x * 256 + t;
    float xv[32];
    #pragma unroll
    for (int ci = 0; ci < 32; ++ci) xv[ci] = x[ci * 65536 + s];
    float lsum = 0.f, lsq = 0.f;
    for (int o = 0; o < 128; ++o) {
        float acc = Be[o];
        const float4* wr = (const float4*)&We[o * 32];
        #pragma unroll
        for (int c4 = 0; c4 < 8; ++c4) {
            float4 w = wr[c4];
            acc += w.x * xv[c4*4] + w.y * xv[c4*4+1] + w.z * xv[c4*4+2] + w.w * xv[c4*4+3];
        }
        h1[o * 65536 + s] = acc;
        lsum += acc; lsq += acc * acc;
    }
    block_reduce2(lsum, lsq, sm);
    if (t == 0) { atomicAdd(&stats[2], lsum); atomicAdd(&stats[3], lsq); }
}

// ---------------- K2: GN1 apply + GELU + write padded spatial-major P[18^4][128] ----------------
__global__ __launch_bounds__(256) void k2_gn1_pad(
    const float* __restrict__ h1, float* __restrict__ P, const float* __restrict__ stats,
    const float* __restrict__ gw, const float* __restrict__ gb)
{
    __shared__ float tile[128 * 65];
    float mu = stats[2] * (1.f / 8388608.f);
    float var = stats[3] * (1.f / 8388608.f) - mu * mu;
    float rs = rsqrtf(var + EPSV);
    int t = threadIdx.x;
    int sbase = blockIdx.x * 64;
    for (int p = 0; p < 32; ++p) {
        int idx = p * 256 + t;
        int ci = idx >> 6, sl = idx & 63;
        float v = h1[ci * 65536 + sbase + sl];
        v = (v - mu) * rs * gw[ci] + gb[ci];
        tile[ci * 65 + sl] = gelu_exact(v);
    }
    __syncthreads();
    for (int p = 0; p < 32; ++p) {
        int idx = p * 256 + t;
        int r = idx >> 7, ci = idx & 127;
        int s = sbase + r;
        int w = s & 15, z = (s >> 4) & 15, y = (s >> 8) & 15, xx = s >> 12;
        int prow = (((xx + 1) * 18 + y + 1) * 18 + z + 1) * 18 + w + 1;
        P[prow * 128 + ci] = tile[ci * 65 + r];
    }
}

// ---------------- K3: 3^4 conv 128->128, pad 1, + GN2 stats ----------------
// Block: 64 spatial (4 w-lines at fixed X,Y) x 128 out-ch. 256 threads, 32 acc each.
#define PLSTRIDE 132
__global__ __launch_bounds__(256) void k3_conv2(
    const float* __restrict__ P, const bf16* __restrict__ wt,
    float* __restrict__ h2, float* __restrict__ stats)
{
    __shared__ float Pl[64 * PLSTRIDE];  // 33.8 KB
    __shared__ float Wl[32 * 128];       // 16 KB
    __shared__ float sm[16];
    int t = threadIdx.x;
    int b = blockIdx.x;
    int X = b >> 6, Y = (b >> 2) & 15, Z0 = (b & 3) * 4;
    int w = t & 15, g = t >> 4;          // o = g*8 .. g*8+7
    float acc[4][8];
    #pragma unroll
    for (int k = 0; k < 4; ++k)
        #pragma unroll
        for (int j = 0; j < 8; ++j) acc[k][j] = 0.f;

    for (int tap = 0; tap < 81; ++tap) {
        int kx = tap / 27, ky = (tap / 9) % 3, kz = (tap / 3) % 3, kw = tap % 3;
        __syncthreads();   // previous-tap readers done before Pl overwrite
        // stage P: 4 chunks of 16 rows x 128 ci (each chunk contiguous in P)
        #pragma unroll
        for (int k = 0; k < 4; ++k) {
            int prow0 = (((X + kx) * 18 + (Y + ky)) * 18 + (Z0 + k + kz)) * 18 + kw;
            const float4* src = (const float4*)(P + prow0 * 128);
            #pragma unroll
            for (int pass = 0; pass < 2; ++pass) {
                int f4 = pass * 256 + t;      // 0..511
                int row = f4 >> 5;            // 0..15
                int col4 = f4 & 31;
                *(float4*)&Pl[(k * 16 + row) * PLSTRIDE + col4 * 4] = src[f4];
            }
        }
        for (int cc = 0; cc < 4; ++cc) {
            __syncthreads();  // Wl readers done (and Pl staged, for cc==0)
            {   // stage 32ci x 128o weights, bf16 -> f32
                const uint4* wsrc = (const uint4*)(wt + tap * 16384 + cc * 4096);
                uint4 va = wsrc[t], vb = wsrc[t + 256];
                float2 p0 = bf2f(va.x), p1 = bf2f(va.y), p2 = bf2f(va.z), p3 = bf2f(va.w);
                *(float4*)&Wl[t * 8]     = make_float4(p0.x, p0.y, p1.x, p1.y);
                *(float4*)&Wl[t * 8 + 4] = make_float4(p2.x, p2.y, p3.x, p3.y);
                p0 = bf2f(vb.x); p1 = bf2f(vb.y); p2 = bf2f(vb.z); p3 = bf2f(vb.w);
                *(float4*)&Wl[2048 + t * 8]     = make_float4(p0.x, p0.y, p1.x, p1.y);
                *(float4*)&Wl[2048 + t * 8 + 4] = make_float4(p2.x, p2.y, p3.x, p3.y);
            }
            __syncthreads();
            #pragma unroll
            for (int cil = 0; cil < 32; ++cil) {
                float pv[4];
                #pragma unroll
                for (int k = 0; k < 4; ++k)
                    pv[k] = Pl[(k * 16 + w) * PLSTRIDE + cc * 32 + cil];
                const float4* wr = (const float4*)&Wl[cil * 128 + g * 8];
                float4 w0 = wr[0], w1v = wr[1];
                #pragma unroll
                for (int k = 0; k < 4; ++k) {
                    acc[k][0] += pv[k] * w0.x;  acc[k][1] += pv[k] * w0.y;
                    acc[k][2] += pv[k] * w0.z;  acc[k][3] += pv[k] * w0.w;
                    acc[k][4] += pv[k] * w1v.x; acc[k][5] += pv[k] * w1v.y;
                    acc[k][6] += pv[k] * w1v.z; acc[k][7] += pv[k] * w1v.w;
                }
            }
        }
    }
    float lsum = 0.f, lsq = 0.f;
    int sbaseXY = (X * 16 + Y) * 16;
    #pragma unroll
    for (int k = 0; k < 4; ++k) {
        int s = (sbaseXY + Z0 + k) * 16 + w;
        #pragma unroll
        for (int j = 0; j < 8; ++j) {
            float v = acc[k][j];
            h2[(g * 8 + j) * 65536 + s] = v;
            lsum += v; lsq += v * v;
        }
    }
    __syncthreads();
    block_reduce2(lsum, lsq, sm);
    if (t == 0) { atomicAdd(&stats[4], lsum); atomicAdd(&stats[5], lsq); }
}

// ---------------- K4: GN2 apply + GELU in place + per-channel sums for SE ----------------
__global__ __launch_bounds__(256) void k4_gn2_se(
    float* __restrict__ h2, const float* __restrict__ stats,
    const float* __restrict__ gw, const float* __restrict__ gb,
    float* __restrict__ chansum)
{
    __shared__ float sm[4];
    float mu = stats[4] * (1.f / 8388608.f);
    float var = stats[5] * (1.f / 8388608.f) - mu * mu;
    float rs = rsqrtf(var + EPSV);
    int chan = blockIdx.x >> 4, seg = blockIdx.x & 15;
    float w = gw[chan], bb = gb[chan];
    float lsum = 0.f;
    int base = chan * 65536 + seg * 4096;
    for (int k = 0; k < 16; ++k) {
        int i = base + k * 256 + threadIdx.x;
        float v = gelu_exact((h2[i] - mu) * rs * w + bb);
        h2[i] = v;
        lsum += v;
    }
    #pragma unroll
    for (int off = 32; off > 0; off >>= 1) lsum += __shfl_down(lsum, off);
    int lane = threadIdx.x & 63, wid = threadIdx.x >> 6;
    if (lane == 0) sm[wid] = lsum;
    __syncthreads();
    if (threadIdx.x == 0) atomicAdd(&chansum[chan], sm[0] + sm[1] + sm[2] + sm[3]);
}

// ---------------- K5: SE MLP -> per-channel sigmoid scale ----------------
__global__ void k5_se(const float* __restrict__ chansum,
                      const float* __restrict__ sw1, const float* __restrict__ sw2,
                      float* __restrict__ sescale)
{
    __shared__ float ym[128];
    __shared__ float t1[8];
    int t = threadIdx.x;  // 128 threads
    ym[t] = chansum[t] * (1.f / 65536.f);
    __syncthreads();
    if (t < 8) {
        float a = 0.f;
        for (int o = 0; o < 128; ++o) a += sw1[t * 128 + o] * ym[o];
        t1[t] = gelu_exact(a);
    }
    __syncthreads();
    float a = 0.f;
    #pragma unroll
    for (int d = 0; d < 8; ++d) a += sw2[t * 8 + d] * t1[d];
    sescale[t] = 1.f / (1.f + expf(-a));
}

// ---------------- K6: conv3 (128->32) with SE scale folded, + GN3 stats ----------------
__global__ __launch_bounds__(256) void k6_conv3(
    const float* __restrict__ h2, const float* __restrict__ w3,
    const float* __restrict__ sescale,
    float* __restrict__ h3, float* __restrict__ stats)
{
    __shared__ float We[128 * 32];   // [ci][oc]
    __shared__ float sm[16];
    int t = threadIdx.x;
    for (int i = t; i < 4096; i += 256) {
        int ci = i >> 5, oc = i & 31;
        We[i] = w3[oc * 128 + ci] * sescale[ci];
    }
    __syncthreads();
    int s = blockIdx.x * 256 + t;
    float acc[32];
    #pragma unroll
    for (int j = 0; j < 32; ++j) acc[j] = 0.f;
    for (int ci = 0; ci < 128; ++ci) {
        float hv = h2[ci * 65536 + s];
        const float4* wr = (const float4*)&We[ci * 32];
        #pragma unroll
        for (int j4 = 0; j4 < 8; ++j4) {
            float4 wv = wr[j4];
            acc[j4*4+0] += hv * wv.x; acc[j4*4+1] += hv * wv.y;
            acc[j4*4+2] += hv * wv.z; acc[j4*4+3] += hv * wv.w;
        }
    }
    float ls = 0.f, lq = 0.f;
    #pragma unroll
    for (int j = 0; j < 32; ++j) {
        float v = acc[j];
        h3[j * 65536 + s] = v;
        ls += v; lq += v * v;
    }
    block_reduce2(ls, lq, sm);
    if (t == 0) { atomicAdd(&stats[6], ls); atomicAdd(&stats[7], lq); }
}

// ---------------- K7: GN3 apply -> out ----------------
__global__ __launch_bounds__(256) void k7_gn3(
    const float* __restrict__ h3, const float* __restrict__ stats,
    const float* __restrict__ gw, const float* __restrict__ gb,
    float* __restrict__ out)
{
    float mu = stats[6] * (1.f / 2097152.f);
    float var = stats[7] * (1.f / 2097152.f) - mu * mu;
    float rs = rsqrtf(var + EPSV);
    int idx = blockIdx.x * 256 + threadIdx.x;
    int c = idx >> 16;
    out[idx] = (h3[idx] - mu) * rs * gw[c] + gb[c];
}

// ---------------- launch ----------------
extern "C" void kernel_launch(void* const* d_in, const int* in_sizes, int n_in,
                              void* d_out, int out_size, void* d_ws, size_t ws_size,
                              hipStream_t stream)
{
    const float* x    = (const float*)d_in[0];
    const float* g0w  = (const float*)d_in[1];
    const float* g0b  = (const float*)d_in[2];
    const float* w1   = (const float*)d_in[3];
    const float* gn1w = (const float*)d_in[4];
    const float* gn1b = (const float*)d_in[5];
    const float* w2   = (const float*)d_in[6];
    const float* gn2w = (const float*)d_in[7];
    const float* gn2b = (const float*)d_in[8];
    const float* sw1  = (const float*)d_in[9];
    const float* sw2  = (const float*)d_in[10];
    const float* w3   = (const float*)d_in[11];
    const float* gn3w = (const float*)d_in[12];
    const float* gn3b = (const float*)d_in[13];
    float* out = (float*)d_out;

    char* ws = (char*)d_ws;
    float* stats   = (float*)ws;            // [0..7] sums, [64..191] chansum, [192..319] sescale
    float* chansum = stats + 64;
    float* sescale = stats + 192;
    bf16*  wt   = (bf16*)(ws + 4096);                 // 81*128*128 bf16 = 2.65 MB
    float* P    = (float*)(ws + 2658304);             // 18^4 x 128 f32 = 53.7 MB
    float* hbuf = (float*)(ws + 56406016);            // h1, then h2 (33.5 MB)
    float* h3   = (float*)(ws + 89960448);            // 8.4 MB

    hipMemsetAsync(stats, 0, 4096, stream);
    hipMemsetAsync(P, 0, (size_t)104976 * 128 * 4, stream);
    kw_transpose<<<5184, 256, 0, stream>>>(w2, wt);
    k0_stats_x<<<1024, 256, 0, stream>>>(x, stats);
    k1_conv1<<<256, 256, 0, stream>>>(x, w1, g0w, g0b, hbuf, stats);
    k2_gn1_pad<<<1024, 256, 0, stream>>>(hbuf, P, stats, gn1w, gn1b);
    k3_conv2<<<1024, 256, 0, stream>>>(P, wt, hbuf, stats);
    k4_gn2_se<<<2048, 256, 0, stream>>>(hbuf, stats, gn2w, gn2b, chansum);
    k5_se<<<1, 128, 0, stream>>>(chansum, sw1, sw2, sescale);
    k6_conv3<<<256, 256, 0, stream>>>(hbuf, w3, sescale, h3, stats);
    k7_gn3<<<8192, 256, 0, stream>>>(h3, stats, gn3w, gn3b, out);
}

// Round 3
// 399.744 us; speedup vs baseline: 5.9346x; 5.9346x over previous
//
#include <hip/hip_runtime.h>
#include <hip/hip_bf16.h>
#include <math.h>

typedef __hip_bfloat16 bf16;
typedef short bf16x8 __attribute__((ext_vector_type(8)));
typedef float f32x4 __attribute__((ext_vector_type(4)));

#define EPSV 1e-5f

__device__ __forceinline__ float gelu_exact(float x) {
    return 0.5f * x * (1.0f + erff(x * 0.70710678118654752f));
}

__device__ __forceinline__ void block_reduce2(float& a, float& b, float* sm) {
    #pragma unroll
    for (int off = 32; off > 0; off >>= 1) {
        a += __shfl_down(a, off);
        b += __shfl_down(b, off);
    }
    int lane = threadIdx.x & 63, wid = threadIdx.x >> 6;
    int nw = blockDim.x >> 6;
    if (lane == 0) { sm[wid*2] = a; sm[wid*2+1] = b; }
    __syncthreads();
    if (threadIdx.x == 0) {
        for (int i = 1; i < nw; ++i) { a += sm[i*2]; b += sm[i*2+1]; }
    }
}

__device__ __forceinline__ unsigned pk_bf2(float lo, float hi) {
    union { __hip_bfloat162 b2; unsigned u; } cv;
    cv.b2 = __float22bfloat162_rn(make_float2(lo, hi));
    return cv.u;
}

__device__ __forceinline__ void gload_lds16(const void* g, void* l) {
    __builtin_amdgcn_global_load_lds(
        (const __attribute__((address_space(1))) void*)g,
        (__attribute__((address_space(3))) void*)l, 16, 0, 0);
}

// ---------------- K0: GN0 stats over x ----------------
__global__ __launch_bounds__(256) void k0_stats_x(const float* __restrict__ x,
                                                  float* __restrict__ stats) {
    __shared__ float sm[16];
    const float4* x4 = (const float4*)x;
    int idx = blockIdx.x * 256 + threadIdx.x;
    float s = 0.f, q = 0.f;
    for (int i = idx; i < (1 << 19); i += gridDim.x * 256) {
        float4 v = x4[i];
        s += v.x + v.y + v.z + v.w;
        q += v.x*v.x + v.y*v.y + v.z*v.z + v.w*v.w;
    }
    block_reduce2(s, q, sm);
    if (threadIdx.x == 0) { atomicAdd(&stats[0], s); atomicAdd(&stats[1], q); }
}

// ---------------- KW: w2 [o][ci][tap] -> wt2 [tap][o][ci] (bf16) ----------------
__global__ __launch_bounds__(256) void kw_transpose(const float* __restrict__ w2,
                                                    bf16* __restrict__ wt2) {
    int idx = blockIdx.x * 256 + threadIdx.x;
    if (idx >= 81 * 128 * 128) return;
    int tap = idx >> 14;
    int r = idx & 16383;
    int o = r >> 7;
    int ci = r & 127;
    wt2[idx] = __float2bfloat16(w2[(o * 128 + ci) * 81 + tap]);
}

// ---------------- K1: GN0-apply folded into conv1 (32->128), + GN1 stats ----------------
__global__ __launch_bounds__(256) void k1_conv1(
    const float* __restrict__ x, const float* __restrict__ w1,
    const float* __restrict__ g0w, const float* __restrict__ g0b,
    float* __restrict__ h1, float* __restrict__ stats)
{
    __shared__ float We[128 * 32];
    __shared__ float Be[128];
    __shared__ float sm[16];
    float mu = stats[0] * (1.f / 2097152.f);
    float var = stats[1] * (1.f / 2097152.f) - mu * mu;
    float rs = rsqrtf(var + EPSV);
    int t = threadIdx.x;
    for (int i = t; i < 128 * 32; i += 256) {
        int ci = i & 31;
        We[i] = w1[i] * g0w[ci] * rs;
    }
    if (t < 128) {
        float acc = 0.f;
        for (int ci = 0; ci < 32; ++ci)
            acc += w1[t * 32 + ci] * (g0b[ci] - mu * rs * g0w[ci]);
        Be[t] = acc;
    }
    __syncthreads();
    int s = blockIdx.x * 256 + t;
    float xv[32];
    #pragma unroll
    for (int ci = 0; ci < 32; ++ci) xv[ci] = x[ci * 65536 + s];
    float lsum = 0.f, lsq = 0.f;
    for (int o = 0; o < 128; ++o) {
        float acc = Be[o];
        const float4* wr = (const float4*)&We[o * 32];
        #pragma unroll
        for (int c4 = 0; c4 < 8; ++c4) {
            float4 w = wr[c4];
            acc += w.x * xv[c4*4] + w.y * xv[c4*4+1] + w.z * xv[c4*4+2] + w.w * xv[c4*4+3];
        }
        h1[o * 65536 + s] = acc;
        lsum += acc; lsq += acc * acc;
    }
    block_reduce2(lsum, lsq, sm);
    if (t == 0) { atomicAdd(&stats[2], lsum); atomicAdd(&stats[3], lsq); }
}

// ---------------- K2: GN1 apply + GELU -> padded bf16 P[18^4][128] ----------------
__global__ __launch_bounds__(256) void k2_gn1_pad(
    const float* __restrict__ h1, bf16* __restrict__ P, const float* __restrict__ stats,
    const float* __restrict__ gw, const float* __restrict__ gb)
{
    __shared__ float tile[128 * 65];
    float mu = stats[2] * (1.f / 8388608.f);
    float var = stats[3] * (1.f / 8388608.f) - mu * mu;
    float rs = rsqrtf(var + EPSV);
    int t = threadIdx.x;
    int sbase = blockIdx.x * 64;
    for (int p = 0; p < 32; ++p) {
        int idx = p * 256 + t;
        int ci = idx >> 6, sl = idx & 63;
        float v = h1[ci * 65536 + sbase + sl];
        v = (v - mu) * rs * gw[ci] + gb[ci];
        tile[ci * 65 + sl] = gelu_exact(v);
    }
    __syncthreads();
    for (int p = 0; p < 4; ++p) {
        int idx = p * 256 + t;          // 1024 units: 64 rows x 16 ci-groups
        int r = idx >> 4, cg = idx & 15;
        int s = sbase + r;
        int w = s & 15, z = (s >> 4) & 15, y = (s >> 8) & 15, xx = s >> 12;
        int prow = (((xx + 1) * 18 + y + 1) * 18 + z + 1) * 18 + w + 1;
        int c0 = cg * 8;
        uint4 u;
        u.x = pk_bf2(tile[(c0+0)*65 + r], tile[(c0+1)*65 + r]);
        u.y = pk_bf2(tile[(c0+2)*65 + r], tile[(c0+3)*65 + r]);
        u.z = pk_bf2(tile[(c0+4)*65 + r], tile[(c0+5)*65 + r]);
        u.w = pk_bf2(tile[(c0+6)*65 + r], tile[(c0+7)*65 + r]);
        *(uint4*)((char*)P + ((size_t)prow * 256 + c0 * 2)) = u;
    }
}

// ---------------- K3: 3^4 conv 128->128 via MFMA bf16, + GN2 stats ----------------
// Grid 512 = (X 16, Y 16, Zhalf 2). 256 thr = 4 waves; wave tile 64 spatial x 64 o.
__global__ __launch_bounds__(256) void k3_conv2(
    const bf16* __restrict__ P, const bf16* __restrict__ wt2,
    float* __restrict__ h2, float* __restrict__ stats)
{
    __shared__ __align__(16) short As[23040];   // 180 rows x 128 ci, XOR-swizzled
    __shared__ __align__(16) short Ws[16384];   // 128 o   x 128 ci, XOR-swizzled
    __shared__ float sm[16];
    int t = threadIdx.x;
    int lane = t & 63, ww = t >> 6;
    int lo = lane & 15, hi = lane >> 4;
    int b = blockIdx.x;
    int X = b >> 5, Y = (b >> 1) & 15, Z0 = (b & 1) * 8;
    int zg = ww >> 1, og = ww & 1;

    // B (weights) fragment row bases — tap-invariant
    int wbase[4], wxor[4];
    #pragma unroll
    for (int n = 0; n < 4; ++n) {
        int row = og * 64 + n * 16 + lo;
        wbase[n] = row << 8;
        wxor[n] = (row & 7) << 4;
    }

    f32x4 acc[4][4];
    #pragma unroll
    for (int m = 0; m < 4; ++m)
        #pragma unroll
        for (int n = 0; n < 4; ++n) acc[m][n] = (f32x4){0.f, 0.f, 0.f, 0.f};

    const char* Pb = (const char*)P;
    const char* Wb = (const char*)wt2;

    for (int kxy = 0; kxy < 9; ++kxy) {
        int kx = kxy / 3, ky = kxy - kx * 3;
        __syncthreads();   // prior readers of As done
        // stage 180 contiguous P rows: (X+kx, Y+ky, z'=Z0..Z0+9, w'=0..17) x 128ci bf16
        int rowstart = ((X + kx) * 18 + (Y + ky)) * 324 + Z0 * 18;
        const char* gA = Pb + (size_t)rowstart * 256;
        for (int c = ww; c < 45; c += 4) {
            int L = c * 1024 + lane * 16;
            int srcoff = L ^ (((L >> 8) & 7) << 4);   // pre-swizzle source (rule #21)
            gload_lds16(gA + srcoff, (char*)As + c * 1024);
        }
        for (int t9 = 0; t9 < 9; ++t9) {
            int kz = t9 / 3, kw = t9 - kz * 3;
            int tap = kxy * 9 + t9;
            __syncthreads();   // prior readers of Ws done (+ As loads drained)
            const char* gW = Wb + (size_t)tap * 32768;
            for (int c = ww; c < 32; c += 4) {
                int L = c * 1024 + lane * 16;
                int srcoff = L ^ (((L >> 8) & 7) << 4);
                gload_lds16(gW + srcoff, (char*)Ws + c * 1024);
            }
            int abase[4], axor[4];
            #pragma unroll
            for (int m = 0; m < 4; ++m) {
                int row = (zg * 4 + m + kz) * 18 + lo + kw;
                abase[m] = row << 8;
                axor[m] = (row & 7) << 4;
            }
            __syncthreads();   // As + Ws ready
            #pragma unroll
            for (int kk = 0; kk < 4; ++kk) {
                int cb = kk * 64 + hi * 16;
                bf16x8 a[4], bb[4];
                #pragma unroll
                for (int m = 0; m < 4; ++m)
                    a[m] = *(const bf16x8*)((const char*)As + abase[m] + (cb ^ axor[m]));
                #pragma unroll
                for (int n = 0; n < 4; ++n)
                    bb[n] = *(const bf16x8*)((const char*)Ws + wbase[n] + (cb ^ wxor[n]));
                #pragma unroll
                for (int m = 0; m < 4; ++m)
                    #pragma unroll
                    for (int n = 0; n < 4; ++n)
                        acc[m][n] = __builtin_amdgcn_mfma_f32_16x16x32_bf16(
                            a[m], bb[n], acc[m][n], 0, 0, 0);
            }
        }
    }

    // epilogue: D frag col(lane&15)=o, row((lane>>4)*4+e)=w  -> float4 store along w
    float ls = 0.f, lq = 0.f;
    int sXY = (X * 16 + Y) * 16;
    #pragma unroll
    for (int m = 0; m < 4; ++m) {
        int z = Z0 + zg * 4 + m;
        int s = (sXY + z) * 16 + hi * 4;
        #pragma unroll
        for (int n = 0; n < 4; ++n) {
            int o = og * 64 + n * 16 + lo;
            *(f32x4*)(h2 + (size_t)o * 65536 + s) = acc[m][n];
            #pragma unroll
            for (int e = 0; e < 4; ++e) { float v = acc[m][n][e]; ls += v; lq += v * v; }
        }
    }
    __syncthreads();
    block_reduce2(ls, lq, sm);
    if (t == 0) { atomicAdd(&stats[4], ls); atomicAdd(&stats[5], lq); }
}

// ---------------- K4: GN2 apply + GELU in place + per-channel sums for SE ----------------
__global__ __launch_bounds__(256) void k4_gn2_se(
    float* __restrict__ h2, const float* __restrict__ stats,
    const float* __restrict__ gw, const float* __restrict__ gb,
    float* __restrict__ chansum)
{
    __shared__ float sm[4];
    float mu = stats[4] * (1.f / 8388608.f);
    float var = stats[5] * (1.f / 8388608.f) - mu * mu;
    float rs = rsqrtf(var + EPSV);
    int chan = blockIdx.x >> 4, seg = blockIdx.x & 15;
    float w = gw[chan], bb = gb[chan];
    float lsum = 0.f;
    int base = chan * 65536 + seg * 4096;
    for (int k = 0; k < 16; ++k) {
        int i = base + k * 256 + threadIdx.x;
        float v = gelu_exact((h2[i] - mu) * rs * w + bb);
        h2[i] = v;
        lsum += v;
    }
    #pragma unroll
    for (int off = 32; off > 0; off >>= 1) lsum += __shfl_down(lsum, off);
    int lane = threadIdx.x & 63, wid = threadIdx.x >> 6;
    if (lane == 0) sm[wid] = lsum;
    __syncthreads();
    if (threadIdx.x == 0) atomicAdd(&chansum[chan], sm[0] + sm[1] + sm[2] + sm[3]);
}

// ---------------- K5: SE MLP -> per-channel sigmoid scale ----------------
__global__ void k5_se(const float* __restrict__ chansum,
                      const float* __restrict__ sw1, const float* __restrict__ sw2,
                      float* __restrict__ sescale)
{
    __shared__ float ym[128];
    __shared__ float t1[8];
    int t = threadIdx.x;  // 128 threads
    ym[t] = chansum[t] * (1.f / 65536.f);
    __syncthreads();
    if (t < 8) {
        float a = 0.f;
        for (int o = 0; o < 128; ++o) a += sw1[t * 128 + o] * ym[o];
        t1[t] = gelu_exact(a);
    }
    __syncthreads();
    float a = 0.f;
    #pragma unroll
    for (int d = 0; d < 8; ++d) a += sw2[t * 8 + d] * t1[d];
    sescale[t] = 1.f / (1.f + expf(-a));
}

// ---------------- K6: conv3 (128->32) with SE scale folded, + GN3 stats ----------------
__global__ __launch_bounds__(256) void k6_conv3(
    const float* __restrict__ h2, const float* __restrict__ w3,
    const float* __restrict__ sescale,
    float* __restrict__ h3, float* __restrict__ stats)
{
    __shared__ float We[128 * 32];   // [ci][oc]
    __shared__ float sm[16];
    int t = threadIdx.x;
    for (int i = t; i < 4096; i += 256) {
        int ci = i >> 5, oc = i & 31;
        We[i] = w3[oc * 128 + ci] * sescale[ci];
    }
    __syncthreads();
    int s = blockIdx.x * 256 + t;
    float acc[32];
    #pragma unroll
    for (int j = 0; j < 32; ++j) acc[j] = 0.f;
    for (int ci = 0; ci < 128; ++ci) {
        float hv = h2[ci * 65536 + s];
        const float4* wr = (const float4*)&We[ci * 32];
        #pragma unroll
        for (int j4 = 0; j4 < 8; ++j4) {
            float4 wv = wr[j4];
            acc[j4*4+0] += hv * wv.x; acc[j4*4+1] += hv * wv.y;
            acc[j4*4+2] += hv * wv.z; acc[j4*4+3] += hv * wv.w;
        }
    }
    float ls = 0.f, lq = 0.f;
    #pragma unroll
    for (int j = 0; j < 32; ++j) {
        float v = acc[j];
        h3[j * 65536 + s] = v;
        ls += v; lq += v * v;
    }
    block_reduce2(ls, lq, sm);
    if (t == 0) { atomicAdd(&stats[6], ls); atomicAdd(&stats[7], lq); }
}

// ---------------- K7: GN3 apply -> out ----------------
__global__ __launch_bounds__(256) void k7_gn3(
    const float* __restrict__ h3, const float* __restrict__ stats,
    const float* __restrict__ gw, const float* __restrict__ gb,
    float* __restrict__ out)
{
    float mu = stats[6] * (1.f / 2097152.f);
    float var = stats[7] * (1.f / 2097152.f) - mu * mu;
    float rs = rsqrtf(var + EPSV);
    int idx = blockIdx.x * 256 + threadIdx.x;
    int c = idx >> 16;
    out[idx] = (h3[idx] - mu) * rs * gw[c] + gb[c];
}

// ---------------- launch ----------------
extern "C" void kernel_launch(void* const* d_in, const int* in_sizes, int n_in,
                              void* d_out, int out_size, void* d_ws, size_t ws_size,
                              hipStream_t stream)
{
    const float* x    = (const float*)d_in[0];
    const float* g0w  = (const float*)d_in[1];
    const float* g0b  = (const float*)d_in[2];
    const float* w1   = (const float*)d_in[3];
    const float* gn1w = (const float*)d_in[4];
    const float* gn1b = (const float*)d_in[5];
    const float* w2   = (const float*)d_in[6];
    const float* gn2w = (const float*)d_in[7];
    const float* gn2b = (const float*)d_in[8];
    const float* sw1  = (const float*)d_in[9];
    const float* sw2  = (const float*)d_in[10];
    const float* w3   = (const float*)d_in[11];
    const float* gn3w = (const float*)d_in[12];
    const float* gn3b = (const float*)d_in[13];
    float* out = (float*)d_out;

    char* ws = (char*)d_ws;
    float* stats   = (float*)ws;            // [0..7] sums, [64..191] chansum, [192..319] sescale
    float* chansum = stats + 64;
    float* sescale = stats + 192;
    bf16*  wt2  = (bf16*)(ws + 4096);                 // 81*128*128 bf16 = 2,654,208 B
    bf16*  P    = (bf16*)(ws + 2658304);              // 18^4 x 128 bf16 = 26,873,856 B
    float* hbuf = (float*)(ws + 29532160);            // h1 then h2, 33,554,432 B
    float* h3   = (float*)(ws + 63086592);            // 8,388,608 B

    hipMemsetAsync(stats, 0, 4096, stream);
    hipMemsetAsync(P, 0, (size_t)104976 * 128 * 2, stream);
    kw_transpose<<<5184, 256, 0, stream>>>(w2, wt2);
    k0_stats_x<<<1024, 256, 0, stream>>>(x, stats);
    k1_conv1<<<256, 256, 0, stream>>>(x, w1, g0w, g0b, hbuf, stats);
    k2_gn1_pad<<<1024, 256, 0, stream>>>(hbuf, P, stats, gn1w, gn1b);
    k3_conv2<<<512, 256, 0, stream>>>(P, wt2, hbuf, stats);
    k4_gn2_se<<<2048, 256, 0, stream>>>(hbuf, stats, gn2w, gn2b, chansum);
    k5_se<<<1, 128, 0, stream>>>(chansum, sw1, sw2, sescale);
    k6_conv3<<<256, 256, 0, stream>>>(hbuf, w3, sescale, h3, stats);
    k7_gn3<<<8192, 256, 0, stream>>>(h3, stats, gn3w, gn3b, out);
}